// Round 1
// 1369.320 us; speedup vs baseline: 1.0504x; 1.0504x over previous
//
#include <hip/hip_runtime.h>

// Grouped SwiGLU MLP, MI355X gfx950.
// Round 2: 8-phase counted-vmcnt schedule (T3+T4+T5) on both GEMMs.
//   gemm1: BM=256 x dual BN=128 (gate+up share A frags), 8 waves, 128KB LDS
//   gemm2: BM=256 x BN=256, 8 waves, 128KB LDS
// LDS per operand = 4 rotating half-buffers of 32 K-columns (buffer for
// (tile t, kk) = (t&1)*2+kk). Stage unit = 2 global_load_lds instr/thread.
// Per 8-phase iteration (2 K-tiles T,T+1):
//   p0: rd A(T,k0)+Bg(T,k0) | st B1(T+1) ; p1: rd Bu(T,k0) | st A0(T+2)
//   p2: rd A(T,k1)+Bg(T,k1) | st B0(T+2) ; p3: rd Bu(T,k1) | st A1(T+2) vmcnt(6)
//   p4..p7: same for T+1, staging B1(T+2), A0/B0/A1(T+3), vmcnt(6) at p7.
// Each stage unit is issued exactly one phase after its buffer's last ds_read
// (gated by the trailing s_barrier); vmcnt(6) leaves the 3 newest units in
// flight and guarantees the next tile resident. Never drains to 0 mid-loop.

#define GN 8
#define DN 1024
#define HN 2048
#define ON 1024

typedef __attribute__((ext_vector_type(8))) short short8;
typedef __attribute__((ext_vector_type(4))) float f32x4;
typedef __attribute__((ext_vector_type(4))) unsigned int u32x4;

#define SBAR() __builtin_amdgcn_sched_barrier(0)
#define BARR() __builtin_amdgcn_s_barrier()

__device__ __forceinline__ void async16(const void* g, void* l) {
  __builtin_amdgcn_global_load_lds(
      (const __attribute__((address_space(1))) void*)g,
      (__attribute__((address_space(3))) void*)l, 16, 0, 0);
}

__device__ __forceinline__ unsigned short f2bf(float f) {
  unsigned int u = __float_as_uint(f);
  u += 0x7FFFu + ((u >> 16) & 1u);  // round-to-nearest-even
  return (unsigned short)(u >> 16);
}

__global__ __launch_bounds__(256) void cvt_f32_bf16(
    const float* __restrict__ in, unsigned short* __restrict__ out, int n) {
  int t = blockIdx.x * 256 + threadIdx.x;
  int i = t * 8;
  if (i >= n) return;
  f32x4 a = *(const f32x4*)(in + i);
  f32x4 b = *(const f32x4*)(in + i + 4);
  u32x4 r;
  r.x = (unsigned)f2bf(a.x) | ((unsigned)f2bf(a.y) << 16);
  r.y = (unsigned)f2bf(a.z) | ((unsigned)f2bf(a.w) << 16);
  r.z = (unsigned)f2bf(b.x) | ((unsigned)f2bf(b.y) << 16);
  r.w = (unsigned)f2bf(b.z) | ((unsigned)f2bf(b.w) << 16);
  *(u32x4*)(out + i) = r;
}

// ---------------- Phase 1: gate/up dual GEMM + SwiGLU -> hidden bf16 --------
// grid 4096 = 32 mt x 16 nt x 8 g (XCD-swizzled), 512 threads (8 waves 2Mx4N).
__global__ __launch_bounds__(512, 2) void gemm1_swiglu(
    const unsigned short* __restrict__ Xb, const unsigned short* __restrict__ Wgb,
    const unsigned short* __restrict__ Wub, unsigned short* __restrict__ Hid) {
  extern __shared__ unsigned short sm[];
  unsigned short* sA = sm;            // 4 bufs x 256x32 = 32768 (64KB)
  unsigned short* sG = sm + 32768;    // 4 bufs x 128x32 = 16384 (32KB)
  unsigned short* sU = sm + 49152;    // 4 bufs x 128x32 = 16384 (32KB)

  const int bid = blockIdx.x;
  const int swz = (bid & 7) * 512 + (bid >> 3);  // 4096 % 8 == 0: bijective
  const int g = swz >> 9;
  const int rem = swz & 511;
  const int m0 = (rem >> 4) * 256;
  const int n0 = (rem & 15) * 128;

  const int tid = threadIdx.x;
  const int lane = tid & 63;
  const int w = tid >> 6;
  const int wm = w >> 2, wn = w & 3;
  const int fr = lane & 15, fc = lane >> 4;
  const int sR = (fc + ((fr >> 1) & 3)) & 3;  // read-side chunk swizzle

  // staging sources (global pre-swizzled so linear LDS write == swizzled tile)
  const unsigned short* aSrc[2];
  unsigned short* aDst[2];
#pragma unroll
  for (int j = 0; j < 2; ++j) {
    int R = j * 128 + w * 16 + (lane >> 2);
    int c = ((lane & 3) - ((R >> 1) & 3)) & 3;
    aSrc[j] = Xb + ((size_t)((m0 + R) * 8 + g)) * DN + c * 8;
    aDst[j] = &sA[(j * 128 + w * 16) * 32];
  }
  const unsigned short *gSrc, *uSrc;
  unsigned short *gDst, *uDst;
  {
    int R = w * 16 + (lane >> 2);
    int c = ((lane & 3) - ((R >> 1) & 3)) & 3;
    gSrc = Wgb + ((size_t)(g * HN + n0 + R)) * DN + c * 8;
    uSrc = Wub + ((size_t)(g * HN + n0 + R)) * DN + c * 8;
    gDst = &sG[(w * 16) * 32];
    uDst = &sU[(w * 16) * 32];
  }

  auto stageA = [&](int t, int kk) {  // 2 loads/thread
    const int buf = (t & 1) * 2 + kk;
    const int ko = t * 64 + kk * 32;
#pragma unroll
    for (int j = 0; j < 2; ++j) async16(aSrc[j] + ko, aDst[j] + buf * 8192);
  };
  auto stageB = [&](int t, int kk) {  // 2 loads/thread (Bg + Bu)
    const int buf = (t & 1) * 2 + kk;
    const int ko = t * 64 + kk * 32;
    async16(gSrc + ko, gDst + buf * 4096);
    async16(uSrc + ko, uDst + buf * 4096);
  };
  auto readA = [&](int t, int kk, short8* a) {
    const unsigned short* p =
        sA + ((t & 1) * 2 + kk) * 8192 + (wm * 128 + fr) * 32 + sR * 8;
#pragma unroll
    for (int mi = 0; mi < 8; ++mi) a[mi] = *(const short8*)(p + mi * 512);
  };
  auto readB = [&](const unsigned short* base, int t, int kk, short8* b) {
    const unsigned short* p =
        base + ((t & 1) * 2 + kk) * 4096 + (wn * 32 + fr) * 32 + sR * 8;
#pragma unroll
    for (int ni = 0; ni < 2; ++ni) b[ni] = *(const short8*)(p + ni * 512);
  };

  f32x4 accg[8][2], accu[8][2];
#pragma unroll
  for (int mi = 0; mi < 8; ++mi)
#pragma unroll
    for (int ni = 0; ni < 2; ++ni) {
      accg[mi][ni] = (f32x4)(0.0f);
      accu[mi][ni] = (f32x4)(0.0f);
    }

  auto mm16 = [&](const short8* a, const short8* b, f32x4(*acc)[2]) {
    __builtin_amdgcn_s_setprio(1);
#pragma unroll
    for (int mi = 0; mi < 8; ++mi)
#pragma unroll
      for (int ni = 0; ni < 2; ++ni)
        acc[mi][ni] = __builtin_amdgcn_mfma_f32_16x16x32_bf16(
            a[mi], b[ni], acc[mi][ni], 0, 0, 0);
    __builtin_amdgcn_s_setprio(0);
  };

  // prologue: 7 units (tile0 full + tile1 A0,B0,A1); vmcnt(6) => tile0 resident
  stageA(0, 0); stageB(0, 0); stageA(0, 1); stageB(0, 1);
  stageA(1, 0); stageB(1, 0); stageA(1, 1);
  asm volatile("s_waitcnt vmcnt(6)" ::: "memory");
  SBAR(); BARR(); SBAR();

  short8 af[8], bg[2], bu[2];
  const int NIT = DN / 128;  // 8
#pragma unroll 1
  for (int i = 0; i < NIT; ++i) {
    const int T = 2 * i;
    const bool full = (i + 1 < NIT);
    // ---- p0 ----
    readA(T, 0, af); readB(sG, T, 0, bg);
    stageB(T + 1, 1);
    SBAR(); BARR(); SBAR();
    mm16(af, bg, accg);
    SBAR(); BARR(); SBAR();
    // ---- p1 ----
    readB(sU, T, 0, bu);
    if (full) stageA(T + 2, 0);
    SBAR(); BARR(); SBAR();
    mm16(af, bu, accu);
    SBAR(); BARR(); SBAR();
    // ---- p2 ----
    readA(T, 1, af); readB(sG, T, 1, bg);
    if (full) stageB(T + 2, 0);
    SBAR(); BARR(); SBAR();
    mm16(af, bg, accg);
    SBAR(); BARR(); SBAR();
    // ---- p3 ----
    readB(sU, T, 1, bu);
    if (full) stageA(T + 2, 1);
    SBAR(); BARR(); SBAR();
    mm16(af, bu, accu);
    if (full) { asm volatile("s_waitcnt vmcnt(6)" ::: "memory"); }
    else      { asm volatile("s_waitcnt vmcnt(0)" ::: "memory"); }
    SBAR(); BARR(); SBAR();
    // ---- p4 ----
    readA(T + 1, 0, af); readB(sG, T + 1, 0, bg);
    if (full) stageB(T + 2, 1);
    SBAR(); BARR(); SBAR();
    mm16(af, bg, accg);
    SBAR(); BARR(); SBAR();
    // ---- p5 ----
    readB(sU, T + 1, 0, bu);
    if (full) stageA(T + 3, 0);
    SBAR(); BARR(); SBAR();
    mm16(af, bu, accu);
    SBAR(); BARR(); SBAR();
    // ---- p6 ----
    readA(T + 1, 1, af); readB(sG, T + 1, 1, bg);
    if (full) stageB(T + 3, 0);
    SBAR(); BARR(); SBAR();
    mm16(af, bg, accg);
    SBAR(); BARR(); SBAR();
    // ---- p7 ----
    readB(sU, T + 1, 1, bu);
    if (full) stageA(T + 3, 1);
    SBAR(); BARR(); SBAR();
    mm16(af, bu, accu);
    if (full) { asm volatile("s_waitcnt vmcnt(6)" ::: "memory"); }
    SBAR(); BARR(); SBAR();
  }

  // epilogue: silu(gate)*up -> bf16 hidden
  const int q = lane >> 4, cl = lane & 15;
#pragma unroll
  for (int mi = 0; mi < 8; ++mi)
#pragma unroll
    for (int ni = 0; ni < 2; ++ni) {
      int hcol = n0 + wn * 32 + ni * 16 + cl;
#pragma unroll
      for (int i2 = 0; i2 < 4; ++i2) {
        int b = m0 + wm * 128 + mi * 16 + q * 4 + i2;
        float gf = accg[mi][ni][i2];
        float uf = accu[mi][ni][i2];
        float hv = (gf / (1.0f + __expf(-gf))) * uf;
        Hid[((size_t)(b * 8 + g)) * HN + hcol] = f2bf(hv);
      }
    }
}

// ---------------- Phase 2: hidden @ Wd^T -> out fp32 ------------------------
// grid 1024 = 32 mt x 4 nt x 8 g (XCD-swizzled), 512 threads (8 waves 2Mx4N).
__global__ __launch_bounds__(512, 2) void gemm2_down(
    const unsigned short* __restrict__ Hid, const unsigned short* __restrict__ Wdb,
    float* __restrict__ Out) {
  extern __shared__ unsigned short sm[];
  unsigned short* sA = sm;            // 4 x 256x32
  unsigned short* sB = sm + 32768;    // 4 x 256x32

  const int bid = blockIdx.x;
  const int swz = (bid & 7) * 128 + (bid >> 3);  // 1024 % 8 == 0
  const int g = swz >> 7;
  const int rem = swz & 127;
  const int m0 = (rem >> 2) * 256;
  const int n0 = (rem & 3) * 256;

  const int tid = threadIdx.x;
  const int lane = tid & 63;
  const int w = tid >> 6;
  const int wm = w >> 2, wn = w & 3;
  const int fr = lane & 15, fc = lane >> 4;
  const int sR = (fc + ((fr >> 1) & 3)) & 3;

  const unsigned short* aSrc[2];
  const unsigned short* bSrc[2];
  unsigned short* aDst[2];
  unsigned short* bDst[2];
#pragma unroll
  for (int j = 0; j < 2; ++j) {
    int R = j * 128 + w * 16 + (lane >> 2);
    int c = ((lane & 3) - ((R >> 1) & 3)) & 3;
    aSrc[j] = Hid + ((size_t)((m0 + R) * 8 + g)) * HN + c * 8;
    bSrc[j] = Wdb + ((size_t)(g * ON + n0 + R)) * HN + c * 8;
    aDst[j] = &sA[(j * 128 + w * 16) * 32];
    bDst[j] = &sB[(j * 128 + w * 16) * 32];
  }

  auto stageA = [&](int t, int kk) {
    const int buf = (t & 1) * 2 + kk;
    const int ko = t * 64 + kk * 32;
#pragma unroll
    for (int j = 0; j < 2; ++j) async16(aSrc[j] + ko, aDst[j] + buf * 8192);
  };
  auto stageB = [&](int t, int kk) {
    const int buf = (t & 1) * 2 + kk;
    const int ko = t * 64 + kk * 32;
#pragma unroll
    for (int j = 0; j < 2; ++j) async16(bSrc[j] + ko, bDst[j] + buf * 8192);
  };
  auto readA = [&](int t, int kk, short8* a) {
    const unsigned short* p =
        sA + ((t & 1) * 2 + kk) * 8192 + (wm * 128 + fr) * 32 + sR * 8;
#pragma unroll
    for (int mi = 0; mi < 8; ++mi) a[mi] = *(const short8*)(p + mi * 512);
  };
  auto readB = [&](int t, int kk, int nb, short8* b) {
    const unsigned short* p =
        sB + ((t & 1) * 2 + kk) * 8192 + (wn * 64 + nb * 16 + fr) * 32 + sR * 8;
#pragma unroll
    for (int nj = 0; nj < 2; ++nj) b[nj] = *(const short8*)(p + nj * 512);
  };

  f32x4 acc[8][4];
#pragma unroll
  for (int mi = 0; mi < 8; ++mi)
#pragma unroll
    for (int ni = 0; ni < 4; ++ni) acc[mi][ni] = (f32x4)(0.0f);

  auto mm16 = [&](const short8* a, const short8* b, int nb) {
    __builtin_amdgcn_s_setprio(1);
#pragma unroll
    for (int mi = 0; mi < 8; ++mi)
#pragma unroll
      for (int nj = 0; nj < 2; ++nj)
        acc[mi][nb + nj] = __builtin_amdgcn_mfma_f32_16x16x32_bf16(
            a[mi], b[nj], acc[mi][nb + nj], 0, 0, 0);
    __builtin_amdgcn_s_setprio(0);
  };

  stageA(0, 0); stageB(0, 0); stageA(0, 1); stageB(0, 1);
  stageA(1, 0); stageB(1, 0); stageA(1, 1);
  asm volatile("s_waitcnt vmcnt(6)" ::: "memory");
  SBAR(); BARR(); SBAR();

  short8 af[8], bf[2];
  const int NIT = HN / 128;  // 16
#pragma unroll 1
  for (int i = 0; i < NIT; ++i) {
    const int T = 2 * i;
    const bool full = (i + 1 < NIT);
    // ---- p0 ----
    readA(T, 0, af); readB(T, 0, 0, bf);
    stageB(T + 1, 1);
    SBAR(); BARR(); SBAR();
    mm16(af, bf, 0);
    SBAR(); BARR(); SBAR();
    // ---- p1 ----
    readB(T, 0, 2, bf);
    if (full) stageA(T + 2, 0);
    SBAR(); BARR(); SBAR();
    mm16(af, bf, 2);
    SBAR(); BARR(); SBAR();
    // ---- p2 ----
    readA(T, 1, af); readB(T, 1, 0, bf);
    if (full) stageB(T + 2, 0);
    SBAR(); BARR(); SBAR();
    mm16(af, bf, 0);
    SBAR(); BARR(); SBAR();
    // ---- p3 ----
    readB(T, 1, 2, bf);
    if (full) stageA(T + 2, 1);
    SBAR(); BARR(); SBAR();
    mm16(af, bf, 2);
    if (full) { asm volatile("s_waitcnt vmcnt(6)" ::: "memory"); }
    else      { asm volatile("s_waitcnt vmcnt(0)" ::: "memory"); }
    SBAR(); BARR(); SBAR();
    // ---- p4 ----
    readA(T + 1, 0, af); readB(T + 1, 0, 0, bf);
    if (full) stageB(T + 2, 1);
    SBAR(); BARR(); SBAR();
    mm16(af, bf, 0);
    SBAR(); BARR(); SBAR();
    // ---- p5 ----
    readB(T + 1, 0, 2, bf);
    if (full) stageA(T + 3, 0);
    SBAR(); BARR(); SBAR();
    mm16(af, bf, 2);
    SBAR(); BARR(); SBAR();
    // ---- p6 ----
    readA(T + 1, 1, af); readB(T + 1, 1, 0, bf);
    if (full) stageB(T + 3, 0);
    SBAR(); BARR(); SBAR();
    mm16(af, bf, 0);
    SBAR(); BARR(); SBAR();
    // ---- p7 ----
    readB(T + 1, 1, 2, bf);
    if (full) stageA(T + 3, 1);
    SBAR(); BARR(); SBAR();
    mm16(af, bf, 2);
    if (full) { asm volatile("s_waitcnt vmcnt(6)" ::: "memory"); }
    SBAR(); BARR(); SBAR();
  }

  const int q = lane >> 4, cl = lane & 15;
#pragma unroll
  for (int mi = 0; mi < 8; ++mi)
#pragma unroll
    for (int ni = 0; ni < 4; ++ni) {
      int o = n0 + wn * 64 + ni * 16 + cl;
#pragma unroll
      for (int i2 = 0; i2 < 4; ++i2) {
        int b = m0 + wm * 128 + mi * 16 + q * 4 + i2;
        Out[((size_t)(b * 8 + g)) * ON + o] = acc[mi][ni][i2];
      }
    }
}

extern "C" void kernel_launch(void* const* d_in, const int* in_sizes, int n_in,
                              void* d_out, int out_size, void* d_ws, size_t ws_size,
                              hipStream_t stream) {
  const float* x  = (const float*)d_in[0];   // [65536, 1024]
  const float* Wg = (const float*)d_in[1];   // [8, 2048, 1024]
  const float* Wu = (const float*)d_in[2];   // [8, 2048, 1024]
  const float* Wd = (const float*)d_in[3];   // [8, 1024, 2048]
  float* out = (float*)d_out;                // [65536, 1024]

  const int NX = 65536 * 1024;
  const int NW = GN * HN * DN;

  unsigned short* xb = (unsigned short*)d_ws;
  unsigned short* wg = xb + (size_t)NX;
  unsigned short* wu = wg + (size_t)NW;
  unsigned short* wd = wu + (size_t)NW;
  unsigned short* hid = wd + (size_t)NW;     // [65536, 2048] bf16

  static bool once = false;
  if (!once) {
    hipFuncSetAttribute((const void*)gemm1_swiglu,
                        hipFuncAttributeMaxDynamicSharedMemorySize, 131072);
    hipFuncSetAttribute((const void*)gemm2_down,
                        hipFuncAttributeMaxDynamicSharedMemorySize, 131072);
    once = true;
  }

  cvt_f32_bf16<<<NX / 8 / 256, 256, 0, stream>>>(x, xb, NX);
  cvt_f32_bf16<<<NW / 8 / 256, 256, 0, stream>>>(Wg, wg, NW);
  cvt_f32_bf16<<<NW / 8 / 256, 256, 0, stream>>>(Wu, wu, NW);
  cvt_f32_bf16<<<NW / 8 / 256, 256, 0, stream>>>(Wd, wd, NW);

  gemm1_swiglu<<<dim3(4096), dim3(512), 131072, stream>>>(xb, wg, wu, hid);
  gemm2_down<<<dim3(1024), dim3(512), 131072, stream>>>(hid, wd, out);
}

// Round 2
// 1354.725 us; speedup vs baseline: 1.0617x; 1.0108x over previous
//
#include <hip/hip_runtime.h>

// Grouped SwiGLU MLP, MI355X gfx950.
// Round 3: 8-phase counted-vmcnt schedule with OPAQUE asm ds_reads.
//   Fragment loads are inline-asm ds_read_b128 (volatile, no mem clobber) so
//   the compiler cannot insert conservative vmcnt drains against the in-flight
//   global_load_lds writes. Per phase: {asm ds_reads | stage issue} -> s_barrier
//   -> s_waitcnt lgkmcnt(0) -> sched_barrier(0) [rule #18] -> setprio(1) 16xMFMA
//   setprio(0) -> s_barrier. Counted vmcnt(6) only at p3/p7.
// Buffer rotation (4 x 32-K-col half-buffers per operand) and vmcnt math are
// unchanged from Round 2 (verified: overwrite >=1 barrier after last read's
// lgkmcnt(0); every read covered by a prior vmcnt(6)).

#define GN 8
#define DN 1024
#define HN 2048
#define ON 1024

typedef __attribute__((ext_vector_type(8))) short short8;
typedef __attribute__((ext_vector_type(4))) float f32x4;
typedef __attribute__((ext_vector_type(4))) unsigned int u32x4;

#define SBAR() __builtin_amdgcn_sched_barrier(0)
#define BARR() __builtin_amdgcn_s_barrier()
#define WAIT_LGKM0()                                       \
  do {                                                     \
    asm volatile("s_waitcnt lgkmcnt(0)" ::: "memory");     \
    __builtin_amdgcn_sched_barrier(0);                     \
  } while (0)

// ds_read_b128 with compile-time byte offset; volatile + opaque to alias analysis.
#define DS128(dst, base, imm)                                                  \
  asm volatile("ds_read_b128 %0, %1 offset:" #imm                              \
               : "=v"(dst)                                                     \
               : "v"((const __attribute__((address_space(3))) unsigned short*)(base)))

__device__ __forceinline__ void async16(const void* g, void* l) {
  __builtin_amdgcn_global_load_lds(
      (const __attribute__((address_space(1))) void*)g,
      (__attribute__((address_space(3))) void*)l, 16, 0, 0);
}

__device__ __forceinline__ unsigned short f2bf(float f) {
  unsigned int u = __float_as_uint(f);
  u += 0x7FFFu + ((u >> 16) & 1u);  // round-to-nearest-even
  return (unsigned short)(u >> 16);
}

__global__ __launch_bounds__(256) void cvt_f32_bf16(
    const float* __restrict__ in, unsigned short* __restrict__ out, int n) {
  int t = blockIdx.x * 256 + threadIdx.x;
  int i = t * 8;
  if (i >= n) return;
  f32x4 a = *(const f32x4*)(in + i);
  f32x4 b = *(const f32x4*)(in + i + 4);
  u32x4 r;
  r.x = (unsigned)f2bf(a.x) | ((unsigned)f2bf(a.y) << 16);
  r.y = (unsigned)f2bf(a.z) | ((unsigned)f2bf(a.w) << 16);
  r.z = (unsigned)f2bf(b.x) | ((unsigned)f2bf(b.y) << 16);
  r.w = (unsigned)f2bf(b.z) | ((unsigned)f2bf(b.w) << 16);
  *(u32x4*)(out + i) = r;
}

// ---------------- Phase 1: gate/up dual GEMM + SwiGLU -> hidden bf16 --------
// grid 4096 = 32 mt x 16 nt x 8 g (XCD-swizzled), 512 threads (8 waves 2Mx4N).
__global__ __launch_bounds__(512, 2) void gemm1_swiglu(
    const unsigned short* __restrict__ Xb, const unsigned short* __restrict__ Wgb,
    const unsigned short* __restrict__ Wub, unsigned short* __restrict__ Hid) {
  extern __shared__ unsigned short sm[];
  unsigned short* sA = sm;            // 4 bufs x 256x32 (64KB)
  unsigned short* sG = sm + 32768;    // 4 bufs x 128x32 (32KB)
  unsigned short* sU = sm + 49152;    // 4 bufs x 128x32 (32KB)

  const int bid = blockIdx.x;
  const int swz = (bid & 7) * 512 + (bid >> 3);  // 4096 % 8 == 0: bijective
  const int g = swz >> 9;
  const int rem = swz & 511;
  const int m0 = (rem >> 4) * 256;
  const int n0 = (rem & 15) * 128;

  const int tid = threadIdx.x;
  const int lane = tid & 63;
  const int w = tid >> 6;
  const int wm = w >> 2, wn = w & 3;
  const int fr = lane & 15, fc = lane >> 4;
  const int sR = (fc + ((fr >> 1) & 3)) & 3;  // read-side chunk swizzle

  // staging sources (global pre-swizzled so linear LDS write == swizzled tile)
  const unsigned short* aSrc[2];
  unsigned short* aDst[2];
#pragma unroll
  for (int j = 0; j < 2; ++j) {
    int R = j * 128 + w * 16 + (lane >> 2);
    int c = ((lane & 3) - ((R >> 1) & 3)) & 3;
    aSrc[j] = Xb + ((size_t)((m0 + R) * 8 + g)) * DN + c * 8;
    aDst[j] = &sA[(j * 128 + w * 16) * 32];
  }
  const unsigned short *gSrc, *uSrc;
  unsigned short *gDst, *uDst;
  {
    int R = w * 16 + (lane >> 2);
    int c = ((lane & 3) - ((R >> 1) & 3)) & 3;
    gSrc = Wgb + ((size_t)(g * HN + n0 + R)) * DN + c * 8;
    uSrc = Wub + ((size_t)(g * HN + n0 + R)) * DN + c * 8;
    gDst = &sG[(w * 16) * 32];
    uDst = &sU[(w * 16) * 32];
  }

  auto stageA = [&](int t, int kk) {  // 2 loads/thread
    const int buf = (t & 1) * 2 + kk;
    const int ko = t * 64 + kk * 32;
#pragma unroll
    for (int j = 0; j < 2; ++j) async16(aSrc[j] + ko, aDst[j] + buf * 8192);
  };
  auto stageB = [&](int t, int kk) {  // 2 loads/thread (Bg + Bu)
    const int buf = (t & 1) * 2 + kk;
    const int ko = t * 64 + kk * 32;
    async16(gSrc + ko, gDst + buf * 4096);
    async16(uSrc + ko, uDst + buf * 4096);
  };
  auto readA = [&](int t, int kk, short8* a) {
    const unsigned short* p =
        sA + ((t & 1) * 2 + kk) * 8192 + (wm * 128 + fr) * 32 + sR * 8;
    DS128(a[0], p, 0);
    DS128(a[1], p, 1024);
    DS128(a[2], p, 2048);
    DS128(a[3], p, 3072);
    DS128(a[4], p, 4096);
    DS128(a[5], p, 5120);
    DS128(a[6], p, 6144);
    DS128(a[7], p, 7168);
  };
  auto readB = [&](const unsigned short* base, int t, int kk, short8* b) {
    const unsigned short* p =
        base + ((t & 1) * 2 + kk) * 4096 + (wn * 32 + fr) * 32 + sR * 8;
    DS128(b[0], p, 0);
    DS128(b[1], p, 1024);
  };

  f32x4 accg[8][2], accu[8][2];
#pragma unroll
  for (int mi = 0; mi < 8; ++mi)
#pragma unroll
    for (int ni = 0; ni < 2; ++ni) {
      accg[mi][ni] = (f32x4)(0.0f);
      accu[mi][ni] = (f32x4)(0.0f);
    }

  auto mm16 = [&](const short8* a, const short8* b, f32x4(*acc)[2]) {
    __builtin_amdgcn_s_setprio(1);
#pragma unroll
    for (int mi = 0; mi < 8; ++mi)
#pragma unroll
      for (int ni = 0; ni < 2; ++ni)
        acc[mi][ni] = __builtin_amdgcn_mfma_f32_16x16x32_bf16(
            a[mi], b[ni], acc[mi][ni], 0, 0, 0);
    __builtin_amdgcn_s_setprio(0);
  };

  // prologue: 7 units (tile0 full + tile1 A0,B0,A1); vmcnt(6) => tile0 resident
  stageA(0, 0); stageB(0, 0); stageA(0, 1); stageB(0, 1);
  stageA(1, 0); stageB(1, 0); stageA(1, 1);
  asm volatile("s_waitcnt vmcnt(6)" ::: "memory");
  BARR();

  short8 af[8], bg[2], bu[2];
  const int NIT = DN / 128;  // 8
#pragma unroll 1
  for (int i = 0; i < NIT; ++i) {
    const int T = 2 * i;
    const bool full = (i + 1 < NIT);
    // ---- p0 ----
    readA(T, 0, af); readB(sG, T, 0, bg);
    stageB(T + 1, 1);
    BARR();
    WAIT_LGKM0();
    mm16(af, bg, accg);
    BARR();
    // ---- p1 ----
    readB(sU, T, 0, bu);
    if (full) stageA(T + 2, 0);
    BARR();
    WAIT_LGKM0();
    mm16(af, bu, accu);
    BARR();
    // ---- p2 ----
    readA(T, 1, af); readB(sG, T, 1, bg);
    if (full) stageB(T + 2, 0);
    BARR();
    WAIT_LGKM0();
    mm16(af, bg, accg);
    BARR();
    // ---- p3 ----
    readB(sU, T, 1, bu);
    if (full) stageA(T + 2, 1);
    BARR();
    WAIT_LGKM0();
    mm16(af, bu, accu);
    if (full) { asm volatile("s_waitcnt vmcnt(6)" ::: "memory"); }
    else      { asm volatile("s_waitcnt vmcnt(0)" ::: "memory"); }
    BARR();
    // ---- p4 ----
    readA(T + 1, 0, af); readB(sG, T + 1, 0, bg);
    if (full) stageB(T + 2, 1);
    BARR();
    WAIT_LGKM0();
    mm16(af, bg, accg);
    BARR();
    // ---- p5 ----
    readB(sU, T + 1, 0, bu);
    if (full) stageA(T + 3, 0);
    BARR();
    WAIT_LGKM0();
    mm16(af, bu, accu);
    BARR();
    // ---- p6 ----
    readA(T + 1, 1, af); readB(sG, T + 1, 1, bg);
    if (full) stageB(T + 3, 0);
    BARR();
    WAIT_LGKM0();
    mm16(af, bg, accg);
    BARR();
    // ---- p7 ----
    readB(sU, T + 1, 1, bu);
    if (full) stageA(T + 3, 1);
    BARR();
    WAIT_LGKM0();
    mm16(af, bu, accu);
    if (full) { asm volatile("s_waitcnt vmcnt(6)" ::: "memory"); }
    BARR();
  }

  // epilogue: silu(gate)*up -> bf16 hidden
  const int q = lane >> 4, cl = lane & 15;
#pragma unroll
  for (int mi = 0; mi < 8; ++mi)
#pragma unroll
    for (int ni = 0; ni < 2; ++ni) {
      int hcol = n0 + wn * 32 + ni * 16 + cl;
#pragma unroll
      for (int i2 = 0; i2 < 4; ++i2) {
        int b = m0 + wm * 128 + mi * 16 + q * 4 + i2;
        float gf = accg[mi][ni][i2];
        float uf = accu[mi][ni][i2];
        float hv = (gf / (1.0f + __expf(-gf))) * uf;
        Hid[((size_t)(b * 8 + g)) * HN + hcol] = f2bf(hv);
      }
    }
}

// ---------------- Phase 2: hidden @ Wd^T -> out fp32 ------------------------
// grid 1024 = 32 mt x 4 nt x 8 g (XCD-swizzled), 512 threads (8 waves 2Mx4N).
__global__ __launch_bounds__(512, 2) void gemm2_down(
    const unsigned short* __restrict__ Hid, const unsigned short* __restrict__ Wdb,
    float* __restrict__ Out) {
  extern __shared__ unsigned short sm[];
  unsigned short* sA = sm;            // 4 x 256x32
  unsigned short* sB = sm + 32768;    // 4 x 256x32

  const int bid = blockIdx.x;
  const int swz = (bid & 7) * 128 + (bid >> 3);  // 1024 % 8 == 0
  const int g = swz >> 7;
  const int rem = swz & 127;
  const int m0 = (rem >> 2) * 256;
  const int n0 = (rem & 3) * 256;

  const int tid = threadIdx.x;
  const int lane = tid & 63;
  const int w = tid >> 6;
  const int wm = w >> 2, wn = w & 3;
  const int fr = lane & 15, fc = lane >> 4;
  const int sR = (fc + ((fr >> 1) & 3)) & 3;

  const unsigned short* aSrc[2];
  const unsigned short* bSrc[2];
  unsigned short* aDst[2];
  unsigned short* bDst[2];
#pragma unroll
  for (int j = 0; j < 2; ++j) {
    int R = j * 128 + w * 16 + (lane >> 2);
    int c = ((lane & 3) - ((R >> 1) & 3)) & 3;
    aSrc[j] = Hid + ((size_t)((m0 + R) * 8 + g)) * HN + c * 8;
    bSrc[j] = Wdb + ((size_t)(g * ON + n0 + R)) * HN + c * 8;
    aDst[j] = &sA[(j * 128 + w * 16) * 32];
    bDst[j] = &sB[(j * 128 + w * 16) * 32];
  }

  auto stageA = [&](int t, int kk) {
    const int buf = (t & 1) * 2 + kk;
    const int ko = t * 64 + kk * 32;
#pragma unroll
    for (int j = 0; j < 2; ++j) async16(aSrc[j] + ko, aDst[j] + buf * 8192);
  };
  auto stageB = [&](int t, int kk) {
    const int buf = (t & 1) * 2 + kk;
    const int ko = t * 64 + kk * 32;
#pragma unroll
    for (int j = 0; j < 2; ++j) async16(bSrc[j] + ko, bDst[j] + buf * 8192);
  };
  auto readA = [&](int t, int kk, short8* a) {
    const unsigned short* p =
        sA + ((t & 1) * 2 + kk) * 8192 + (wm * 128 + fr) * 32 + sR * 8;
    DS128(a[0], p, 0);
    DS128(a[1], p, 1024);
    DS128(a[2], p, 2048);
    DS128(a[3], p, 3072);
    DS128(a[4], p, 4096);
    DS128(a[5], p, 5120);
    DS128(a[6], p, 6144);
    DS128(a[7], p, 7168);
  };
  auto readB = [&](int t, int kk, int nb, short8* b) {
    const unsigned short* p =
        sB + ((t & 1) * 2 + kk) * 8192 + (wn * 64 + nb * 16 + fr) * 32 + sR * 8;
    DS128(b[0], p, 0);
    DS128(b[1], p, 1024);
  };

  f32x4 acc[8][4];
#pragma unroll
  for (int mi = 0; mi < 8; ++mi)
#pragma unroll
    for (int ni = 0; ni < 4; ++ni) acc[mi][ni] = (f32x4)(0.0f);

  auto mm16 = [&](const short8* a, const short8* b, int nb) {
    __builtin_amdgcn_s_setprio(1);
#pragma unroll
    for (int mi = 0; mi < 8; ++mi)
#pragma unroll
      for (int nj = 0; nj < 2; ++nj)
        acc[mi][nb + nj] = __builtin_amdgcn_mfma_f32_16x16x32_bf16(
            a[mi], b[nj], acc[mi][nb + nj], 0, 0, 0);
    __builtin_amdgcn_s_setprio(0);
  };

  stageA(0, 0); stageB(0, 0); stageA(0, 1); stageB(0, 1);
  stageA(1, 0); stageB(1, 0); stageA(1, 1);
  asm volatile("s_waitcnt vmcnt(6)" ::: "memory");
  BARR();

  short8 af[8], bf[2];
  const int NIT = HN / 128;  // 16
#pragma unroll 1
  for (int i = 0; i < NIT; ++i) {
    const int T = 2 * i;
    const bool full = (i + 1 < NIT);
    // ---- p0 ----
    readA(T, 0, af); readB(T, 0, 0, bf);
    stageB(T + 1, 1);
    BARR();
    WAIT_LGKM0();
    mm16(af, bf, 0);
    BARR();
    // ---- p1 ----
    readB(T, 0, 2, bf);
    if (full) stageA(T + 2, 0);
    BARR();
    WAIT_LGKM0();
    mm16(af, bf, 2);
    BARR();
    // ---- p2 ----
    readA(T, 1, af); readB(T, 1, 0, bf);
    if (full) stageB(T + 2, 0);
    BARR();
    WAIT_LGKM0();
    mm16(af, bf, 0);
    BARR();
    // ---- p3 ----
    readB(T, 1, 2, bf);
    if (full) stageA(T + 2, 1);
    BARR();
    WAIT_LGKM0();
    mm16(af, bf, 2);
    if (full) { asm volatile("s_waitcnt vmcnt(6)" ::: "memory"); }
    else      { asm volatile("s_waitcnt vmcnt(0)" ::: "memory"); }
    BARR();
    // ---- p4 ----
    readA(T + 1, 0, af); readB(T + 1, 0, 0, bf);
    if (full) stageB(T + 2, 1);
    BARR();
    WAIT_LGKM0();
    mm16(af, bf, 0);
    BARR();
    // ---- p5 ----
    readB(T + 1, 0, 2, bf);
    if (full) stageA(T + 3, 0);
    BARR();
    WAIT_LGKM0();
    mm16(af, bf, 2);
    BARR();
    // ---- p6 ----
    readA(T + 1, 1, af); readB(T + 1, 1, 0, bf);
    if (full) stageB(T + 3, 0);
    BARR();
    WAIT_LGKM0();
    mm16(af, bf, 0);
    BARR();
    // ---- p7 ----
    readB(T + 1, 1, 2, bf);
    if (full) stageA(T + 3, 1);
    BARR();
    WAIT_LGKM0();
    mm16(af, bf, 2);
    if (full) { asm volatile("s_waitcnt vmcnt(6)" ::: "memory"); }
    BARR();
  }

  const int q = lane >> 4, cl = lane & 15;
#pragma unroll
  for (int mi = 0; mi < 8; ++mi)
#pragma unroll
    for (int ni = 0; ni < 4; ++ni) {
      int o = n0 + wn * 64 + ni * 16 + cl;
#pragma unroll
      for (int i2 = 0; i2 < 4; ++i2) {
        int b = m0 + wm * 128 + mi * 16 + q * 4 + i2;
        Out[((size_t)(b * 8 + g)) * ON + o] = acc[mi][ni][i2];
      }
    }
}

extern "C" void kernel_launch(void* const* d_in, const int* in_sizes, int n_in,
                              void* d_out, int out_size, void* d_ws, size_t ws_size,
                              hipStream_t stream) {
  const float* x  = (const float*)d_in[0];   // [65536, 1024]
  const float* Wg = (const float*)d_in[1];   // [8, 2048, 1024]
  const float* Wu = (const float*)d_in[2];   // [8, 2048, 1024]
  const float* Wd = (const float*)d_in[3];   // [8, 1024, 2048]
  float* out = (float*)d_out;                // [65536, 1024]

  const int NX = 65536 * 1024;
  const int NW = GN * HN * DN;

  unsigned short* xb = (unsigned short*)d_ws;
  unsigned short* wg = xb + (size_t)NX;
  unsigned short* wu = wg + (size_t)NW;
  unsigned short* wd = wu + (size_t)NW;
  unsigned short* hid = wd + (size_t)NW;     // [65536, 2048] bf16

  static bool once = false;
  if (!once) {
    hipFuncSetAttribute((const void*)gemm1_swiglu,
                        hipFuncAttributeMaxDynamicSharedMemorySize, 131072);
    hipFuncSetAttribute((const void*)gemm2_down,
                        hipFuncAttributeMaxDynamicSharedMemorySize, 131072);
    once = true;
  }

  cvt_f32_bf16<<<NX / 8 / 256, 256, 0, stream>>>(x, xb, NX);
  cvt_f32_bf16<<<NW / 8 / 256, 256, 0, stream>>>(Wg, wg, NW);
  cvt_f32_bf16<<<NW / 8 / 256, 256, 0, stream>>>(Wu, wu, NW);
  cvt_f32_bf16<<<NW / 8 / 256, 256, 0, stream>>>(Wd, wd, NW);

  gemm1_swiglu<<<dim3(4096), dim3(512), 131072, stream>>>(xb, wg, wu, hid);
  gemm2_down<<<dim3(1024), dim3(512), 131072, stream>>>(hid, wd, out);
}